// Round 5
// baseline (619.388 us; speedup 1.0000x reference)
//
#include <hip/hip_runtime.h>

typedef __attribute__((ext_vector_type(8))) __bf16 bfrag;
typedef __attribute__((ext_vector_type(16))) float f32x16;
typedef unsigned short ushort_t;

__device__ __forceinline__ unsigned short f2bf(float f) {
    union { unsigned int u; float f; } c; c.f = f;
    unsigned int u = c.u;
    return (unsigned short)((u + 0x7FFFu + ((u >> 16) & 1u)) >> 16);
}
__device__ __forceinline__ float2 bfp(unsigned int u) {
    union { unsigned int u; float f; } lo, hi;
    lo.u = u << 16; hi.u = u & 0xFFFF0000u;
    return make_float2(lo.f, hi.f);
}
__device__ __forceinline__ unsigned int pk2(float a, float b) {
    return ((unsigned)f2bf(b) << 16) | f2bf(a);
}

// ---------------- workspace layout (bytes) ----------------
// feat  bf16 [4][320][640][32]   at 0          (52,428,800)
// costs bf16 [4][256][256][128]  at 52428800   (67,108,864)
// x1    bf16 [4][256][256][64]   at 119537664  (33,554,432)
// x2    bf16 [4][256][256][32]   at 153092096  (16,777,216)
// x3    f32  [4][256][256]       at 169869312  (1,048,576)
// wbf   bf16 packed fusion       at 170917888  (442,368)
// wb1   bf16 packed reg1         at 171360256  (110,592)
// wt2   f32  [kpos][32]          at 171470848  (3,456)

__global__ void omni_transpose_w(const float* __restrict__ src, float* __restrict__ dst,
                                 int cin, int cout, int n) {
    int i = blockIdx.x * 256 + threadIdx.x;
    if (i >= n) return;
    int co = i % cout;
    int t  = i / cout;
    int ci = t % cin;
    int kpos = t / cin;
    dst[i] = src[(co * cin + ci) * 27 + kpos];
}

// pack conv3d weights (OIDHW fp32) into MFMA B-fragment order, bf16.
// layout: [p = c*3+kd][f = tap*4+ks][wn][lane][8]
template<int CI, int CO>
__global__ void omni_pack_w(const float* __restrict__ w, ushort_t* __restrict__ dst) {
    constexpr int WN = CO / 32;
    const int n = (CI / 64) * 3 * 36 * WN * 512;
    int o = blockIdx.x * 256 + threadIdx.x;
    if (o >= n) return;
    const int j = o & 7;
    const int lane = (o >> 3) & 63;
    int r = o >> 9;
    const int wn = r % WN; r /= WN;
    const int f = r % 36;  const int p = r / 36;
    const int tap = f >> 2, ks = f & 3;
    const int c = p / 3, kd = p % 3;
    const int co = wn * 32 + (lane & 31);
    const int ci = c * 64 + ks * 16 + (lane >> 5) * 8 + j;
    const int ky = tap / 3, kx = tap % 3;
    dst[o] = f2bf(w[(((size_t)(co * CI + ci) * 3 + kd) * 3 + ky) * 3 + kx]);
}

// conv2d stride2 pad1 + relu; input NCHW [3,640,1280]; out bf16 channels-last [cam][320][640][32]
__global__ __launch_bounds__(256) void omni_feat_conv(
        const float* __restrict__ c0, const float* __restrict__ c1,
        const float* __restrict__ c2, const float* __restrict__ c3,
        const float* __restrict__ w, ushort_t* __restrict__ feat) {
    __shared__ float wl[864];
    int tid = threadIdx.x;
    for (int i = tid; i < 864; i += 256) wl[i] = w[i];
    __syncthreads();
    int gid = blockIdx.x * 256 + tid;               // 4*320*640
    int ox = gid % 640;
    int t = gid / 640;
    int oy = t % 320;
    int cam = t / 320;
    const float* src = (cam == 0) ? c0 : (cam == 1) ? c1 : (cam == 2) ? c2 : c3;
    float acc[32];
#pragma unroll
    for (int i = 0; i < 32; i++) acc[i] = 0.f;
    for (int ky = 0; ky < 3; ky++) {
        int iy = oy * 2 - 1 + ky;
        if (iy < 0 || iy >= 640) continue;
        for (int kx = 0; kx < 3; kx++) {
            int ix = ox * 2 - 1 + kx;
            if (ix < 0 || ix >= 1280) continue;
#pragma unroll
            for (int ci = 0; ci < 3; ci++) {
                float v = src[(ci * 640 + iy) * 1280 + ix];
#pragma unroll
                for (int co = 0; co < 32; co++)
                    acc[co] += v * wl[((co * 3 + ci) * 3 + ky) * 3 + kx];
            }
        }
    }
    uint4* d4 = (uint4*)(feat + (size_t)gid * 32);
#pragma unroll
    for (int q = 0; q < 4; q++) {
        uint4 v;
        v.x = pk2(fmaxf(acc[8*q+0],0.f), fmaxf(acc[8*q+1],0.f));
        v.y = pk2(fmaxf(acc[8*q+2],0.f), fmaxf(acc[8*q+3],0.f));
        v.z = pk2(fmaxf(acc[8*q+4],0.f), fmaxf(acc[8*q+5],0.f));
        v.w = pk2(fmaxf(acc[8*q+6],0.f), fmaxf(acc[8*q+7],0.f));
        d4[q] = v;
    }
}

// Tiled fused grid_sample + antialiased resize.
#define NXP 42
#define NYP 12
#define NPOS (NXP * NYP)   // 504
__global__ __launch_bounds__(256) void omni_warp_resize(
        const ushort_t* __restrict__ feat, const float* __restrict__ grids,
        ushort_t* __restrict__ costs) {
    __shared__ uint4 smp4[4 * NPOS];   // 32,256 B
    const int tid = threadIdx.x;
    const int bid = blockIdx.x;
    const int tx  = bid & 15;
    const int ty  = (bid >> 4) & 31;
    const int d   = (bid >> 9) & 3;
    const int cam = bid >> 11;
    const int x0 = tx * 16, y0 = ty * 8;
    const int jx_base = 40 * tx - 1;
    const int jy_base = 10 * ty - 1;
    const float* gbase = grids + ((size_t)(cam * 4 + d) * 320) * 640 * 2;
    const ushort_t* fbase = feat + (size_t)cam * 320 * 640 * 32;

    for (int i = tid; i < NPOS; i += 256) {
        const int jy = jy_base + i / NXP;
        const int jx = jx_base + i % NXP;
        float acc[32];
#pragma unroll
        for (int c = 0; c < 32; c++) acc[c] = 0.f;
        if ((unsigned)jy < 320u && (unsigned)jx < 640u) {
            const float gx = gbase[((size_t)jy * 640 + jx) * 2];
            const float gy = gbase[((size_t)jy * 640 + jx) * 2 + 1];
            const float fx = (gx + 1.f) * 320.f - 0.5f;
            const float fy = (gy + 1.f) * 160.f - 0.5f;
            const float x0f = floorf(fx), y0f = floorf(fy);
            const float ax = fx - x0f, ay = fy - y0f;
            const int sx0 = (int)x0f, sy0 = (int)y0f;
            const float tw[4] = {(1.f-ax)*(1.f-ay), ax*(1.f-ay), (1.f-ax)*ay, ax*ay};
            const int xs4[4] = {sx0, sx0+1, sx0, sx0+1};
            const int ys4[4] = {sy0, sy0, sy0+1, sy0+1};
#pragma unroll
            for (int tc = 0; tc < 4; tc++) {
                const int xi = xs4[tc], yi = ys4[tc];
                if (xi < 0 || xi >= 640 || yi < 0 || yi >= 320) continue;
                const float wt = tw[tc];
                const uint4* f4 = (const uint4*)(fbase + ((size_t)yi * 640 + xi) * 32);
#pragma unroll
                for (int q = 0; q < 4; q++) {
                    uint4 v = f4[q];
                    float2 p0 = bfp(v.x), p1 = bfp(v.y), p2 = bfp(v.z), p3 = bfp(v.w);
                    acc[8*q+0] += wt * p0.x; acc[8*q+1] += wt * p0.y;
                    acc[8*q+2] += wt * p1.x; acc[8*q+3] += wt * p1.y;
                    acc[8*q+4] += wt * p2.x; acc[8*q+5] += wt * p2.y;
                    acc[8*q+6] += wt * p3.x; acc[8*q+7] += wt * p3.y;
                }
            }
        }
#pragma unroll
        for (int q = 0; q < 4; q++) {
            uint4 v;
            v.x = pk2(acc[8*q+0], acc[8*q+1]);
            v.y = pk2(acc[8*q+2], acc[8*q+3]);
            v.z = pk2(acc[8*q+4], acc[8*q+5]);
            v.w = pk2(acc[8*q+6], acc[8*q+7]);
            smp4[q * NPOS + i] = v;
        }
    }
    __syncthreads();

    const int half = tid >> 7;
    const int p = tid & 127;
    const int x = x0 + (p & 15);
    const int y = y0 + (p >> 4);

    const float sy = 1.25f * y + 0.125f;
    const int jy0 = (int)ceilf(sy - 1.25f);
    float wy[3]; float sumy = 0.f;
#pragma unroll
    for (int t = 0; t < 3; t++) {
        int j = jy0 + t;
        float w = fmaxf(1.f - fabsf(sy - (float)j) * 0.8f, 0.f);
        if (j < 0 || j > 319) w = 0.f;
        wy[t] = w; sumy += w;
    }
    const float isy = 1.f / sumy;
    const float sx = 2.5f * x + 0.75f;
    const int jx0 = (int)ceilf(sx - 2.5f);
    float wx[5]; float sumx = 0.f;
#pragma unroll
    for (int t = 0; t < 5; t++) {
        int j = jx0 + t;
        float w = fmaxf(1.f - fabsf(sx - (float)j) * 0.4f, 0.f);
        if (j < 0 || j > 639) w = 0.f;
        wx[t] = w; sumx += w;
    }
    const float isx = 1.f / sumx;

    float acc[16];
#pragma unroll
    for (int c = 0; c < 16; c++) acc[c] = 0.f;
#pragma unroll
    for (int a = 0; a < 3; a++) {
        const float wya = wy[a] * isy;
        if (wya <= 0.f) continue;
        const int prow = (jy0 + a) - jy_base;
#pragma unroll
        for (int b = 0; b < 5; b++) {
            const float wr = wya * wx[b] * isx;
            if (wr <= 0.f) continue;
            const int pos = prow * NXP + (jx0 + b) - jx_base;
#pragma unroll
            for (int qq = 0; qq < 2; qq++) {
                uint4 v = smp4[(half * 2 + qq) * NPOS + pos];
                float2 p0 = bfp(v.x), p1 = bfp(v.y), p2 = bfp(v.z), p3 = bfp(v.w);
                acc[8*qq+0] += wr * p0.x; acc[8*qq+1] += wr * p0.y;
                acc[8*qq+2] += wr * p1.x; acc[8*qq+3] += wr * p1.y;
                acc[8*qq+4] += wr * p2.x; acc[8*qq+5] += wr * p2.y;
                acc[8*qq+6] += wr * p3.x; acc[8*qq+7] += wr * p3.y;
            }
        }
    }
    uint4* d4 = (uint4*)(costs + (((size_t)(d * 256 + y) * 256 + x) * 128) + cam * 32 + half * 16);
#pragma unroll
    for (int qq = 0; qq < 2; qq++) {
        uint4 v;
        v.x = pk2(acc[8*qq+0], acc[8*qq+1]);
        v.y = pk2(acc[8*qq+2], acc[8*qq+3]);
        v.z = pk2(acc[8*qq+4], acc[8*qq+5]);
        v.w = pk2(acc[8*qq+6], acc[8*qq+7]);
        d4[qq] = v;
    }
}

// MFMA implicit-GEMM conv3d (3x3x3, pad1) channels-last bf16, relu.
// x-tile XT = 128/WN px; 4 waves of one 32x32 tile each (wm x wn).
// A in LDS [ky][g][xl], xl padded to XLP === 5 (mod 8) -> conflict-free
// b128 reads (consecutive xl) and writes (g-cycling covers 32 banks).
// B held in registers (36 frags per stage).
template<int CI, int CO>
__global__ __launch_bounds__(256, 2) void omni_conv3d_mfma(
        const ushort_t* __restrict__ in,
        const ushort_t* __restrict__ wb,
        ushort_t* __restrict__ out) {
    constexpr int WN  = CO / 32;        // 2 (fusion) or 1 (reg1)
    constexpr int XT  = 128 / WN;       // 64 or 128
    constexpr int XL  = XT + 2;
    constexpr int XLP = XT + 5;         // 69 or 133: (XLP*4)%32==20
    constexpr int NIT = 3 * XL * 8;     // staging uint4 items
    __shared__ ushort_t lds[3 * 8 * XLP * 8];
    const int tid = threadIdx.x;
    const int lane = tid & 63;
    const int wid = tid >> 6;
    const int wn = wid & (WN - 1);
    const int wm = wid / WN;
    const int x0 = blockIdx.x * XT;
    const int y  = blockIdx.y;
    const int d  = blockIdx.z;
    const int mrow = wm * 32 + (lane & 31);
    const int gc   = (lane >> 5);       // k half

    f32x16 acc;
#pragma unroll
    for (int r = 0; r < 16; ++r) acc[r] = 0.f;

    bfrag breg[36];

    for (int c = 0; c < CI / 64; ++c) {
        for (int kd = 0; kd < 3; ++kd) {
            const int dd = d + kd - 1;
            if (dd < 0 || dd > 3) continue;            // block-uniform
            __syncthreads();
            for (int i = tid; i < NIT; i += 256) {
                const int g  = i & 7;
                const int xl = (i >> 3) % XL;
                const int yy = (i >> 3) / XL;
                const int gy = y - 1 + yy;
                const int gx = x0 - 1 + xl;
                uint4 v = make_uint4(0u, 0u, 0u, 0u);
                if ((unsigned)gy < 256u && (unsigned)gx < 256u)
                    v = *(const uint4*)(in + (((size_t)dd * 256 + gy) * 256 + gx) * CI + c * 64 + g * 8);
                *(uint4*)&lds[((yy * 8 + g) * XLP + xl) * 8] = v;
            }
            const int p = c * 3 + kd;
#pragma unroll
            for (int f = 0; f < 36; ++f)
                breg[f] = *(const bfrag*)(wb + (((size_t)p * 36 + f) * WN + wn) * 512 + lane * 8);
            __syncthreads();
#pragma unroll
            for (int ky = 0; ky < 3; ++ky) {
                const int gyy = y - 1 + ky;
                if ((unsigned)gyy >= 256u) continue;   // block-uniform
#pragma unroll
                for (int kx = 0; kx < 3; ++kx) {
                    const int xl = mrow + kx;
#pragma unroll
                    for (int ks = 0; ks < 4; ++ks) {
                        const int g = ks * 2 + gc;
                        const bfrag a = *(const bfrag*)&lds[((ky * 8 + g) * XLP + xl) * 8];
                        acc = __builtin_amdgcn_mfma_f32_32x32x16_bf16(
                            a, breg[(ky * 3 + kx) * 4 + ks], acc, 0, 0, 0);
                    }
                }
            }
        }
    }
    // epilogue: relu + bf16 store. C/D: col=lane&31, row=(r&3)+8*(r>>2)+4*(lane>>5)
#pragma unroll
    for (int r = 0; r < 16; ++r) {
        const int row = (r & 3) + 8 * (r >> 2) + 4 * gc;
        const int px  = x0 + wm * 32 + row;
        const int co  = wn * 32 + (lane & 31);
        out[((size_t)(d * 256 + y) * 256 + px) * CO + co] = f2bf(fmaxf(acc[r], 0.f));
    }
}

// conv3d 32->1, bf16 in, wt2 fp32 [kpos][ci]
__global__ __launch_bounds__(256) void omni_reg2(
        const ushort_t* __restrict__ in, const float* __restrict__ wt2,
        float* __restrict__ out) {
    __shared__ float wl[27 * 32];
    int tid = threadIdx.x;
    for (int i = tid; i < 864; i += 256) wl[i] = wt2[i];
    __syncthreads();
    int gid = blockIdx.x * 256 + tid;               // 4*256*256
    int x = gid & 255;
    int y = (gid >> 8) & 255;
    int d = gid >> 16;
    float acc = 0.f;
    for (int kd = 0; kd < 3; kd++) {
        int dd = d + kd - 1; if (dd < 0 || dd > 3) continue;
        for (int ky = 0; ky < 3; ky++) {
            int yy = y + ky - 1; if (yy < 0 || yy > 255) continue;
            for (int kx = 0; kx < 3; kx++) {
                int xx = x + kx - 1; if (xx < 0 || xx > 255) continue;
                const uint4* f4 = (const uint4*)(in + (((size_t)dd * 256 + yy) * 256 + xx) * 32);
                const float* wp = &wl[((kd * 3 + ky) * 3 + kx) * 32];
#pragma unroll
                for (int q = 0; q < 4; q++) {
                    uint4 v = f4[q];
                    float2 p0 = bfp(v.x), p1 = bfp(v.y), p2 = bfp(v.z), p3 = bfp(v.w);
                    acc += p0.x * wp[8*q+0] + p0.y * wp[8*q+1]
                         + p1.x * wp[8*q+2] + p1.y * wp[8*q+3]
                         + p2.x * wp[8*q+4] + p2.y * wp[8*q+5]
                         + p3.x * wp[8*q+6] + p3.y * wp[8*q+7];
                }
            }
        }
    }
    out[gid] = acc;
}

// depth resize 4->8 + softmax + expectation
__global__ __launch_bounds__(256) void omni_disp(
        const float* __restrict__ x3, float* __restrict__ out) {
    int gid = blockIdx.x * 256 + threadIdx.x;       // 65536
    float v0 = x3[gid];
    float v1 = x3[65536 + gid];
    float v2 = x3[2 * 65536 + gid];
    float v3 = x3[3 * 65536 + gid];
    float l[8];
    l[0] = v0;
    l[1] = 0.75f * v0 + 0.25f * v1;
    l[2] = 0.25f * v0 + 0.75f * v1;
    l[3] = 0.75f * v1 + 0.25f * v2;
    l[4] = 0.25f * v1 + 0.75f * v2;
    l[5] = 0.75f * v2 + 0.25f * v3;
    l[6] = 0.25f * v2 + 0.75f * v3;
    l[7] = v3;
    float m = l[0];
#pragma unroll
    for (int i = 1; i < 8; i++) m = fmaxf(m, l[i]);
    float s = 0.f, e = 0.f;
#pragma unroll
    for (int i = 0; i < 8; i++) {
        float p = expf(l[i] - m);
        s += p; e += p * (float)i;
    }
    out[gid] = e / s;
}

extern "C" void kernel_launch(void* const* d_in, const int* in_sizes, int n_in,
                              void* d_out, int out_size, void* d_ws, size_t ws_size,
                              hipStream_t stream) {
    const float* cam0 = (const float*)d_in[0];
    const float* cam1 = (const float*)d_in[1];
    const float* cam2 = (const float*)d_in[2];
    const float* cam3 = (const float*)d_in[3];
    const float* grids = (const float*)d_in[4];
    const float* w_feat = (const float*)d_in[5];
    const float* w_fusion = (const float*)d_in[6];
    const float* w_reg1 = (const float*)d_in[7];
    const float* w_reg2 = (const float*)d_in[8];

    char* base = (char*)d_ws;
    ushort_t* feat  = (ushort_t*)(base);
    ushort_t* costs = (ushort_t*)(base + 52428800);
    ushort_t* x1    = (ushort_t*)(base + 119537664);
    ushort_t* x2    = (ushort_t*)(base + 153092096);
    float*    x3    = (float*)   (base + 169869312);
    ushort_t* wbf   = (ushort_t*)(base + 170917888);
    ushort_t* wb1   = (ushort_t*)(base + 171360256);
    float*    wt2   = (float*)   (base + 171470848);

    omni_pack_w<128, 64><<<864, 256, 0, stream>>>(w_fusion, wbf);
    omni_pack_w<64, 32><<<216, 256, 0, stream>>>(w_reg1, wb1);
    omni_transpose_w<<<4, 256, 0, stream>>>(w_reg2, wt2, 32, 1, 864);

    omni_feat_conv<<<3200, 256, 0, stream>>>(cam0, cam1, cam2, cam3, w_feat, feat);
    omni_warp_resize<<<8192, 256, 0, stream>>>(feat, grids, costs);
    omni_conv3d_mfma<128, 64><<<dim3(4, 256, 4), 256, 0, stream>>>(costs, wbf, x1);
    omni_conv3d_mfma<64, 32><<<dim3(2, 256, 4), 256, 0, stream>>>(x1, wb1, x2);
    omni_reg2<<<1024, 256, 0, stream>>>(x2, wt2, x3);
    omni_disp<<<256, 256, 0, stream>>>(x3, (float*)d_out);
}

// Round 6
// 586.903 us; speedup vs baseline: 1.0553x; 1.0553x over previous
//
#include <hip/hip_runtime.h>

typedef __attribute__((ext_vector_type(8))) __bf16 bfrag;
typedef __attribute__((ext_vector_type(16))) float f32x16;
typedef unsigned short ushort_t;

__device__ __forceinline__ unsigned short f2bf(float f) {
    union { unsigned int u; float f; } c; c.f = f;
    unsigned int u = c.u;
    return (unsigned short)((u + 0x7FFFu + ((u >> 16) & 1u)) >> 16);
}
__device__ __forceinline__ float2 bfp(unsigned int u) {
    union { unsigned int u; float f; } lo, hi;
    lo.u = u << 16; hi.u = u & 0xFFFF0000u;
    return make_float2(lo.f, hi.f);
}
__device__ __forceinline__ unsigned int pk2(float a, float b) {
    return ((unsigned)f2bf(b) << 16) | f2bf(a);
}

// ---------------- workspace layout (bytes) ----------------
// feat  bf16 [4][320][640][32]   at 0          (52,428,800)
// costs bf16 [4][256][256][128]  at 52428800   (67,108,864)
// x1    bf16 [4][256][256][64]   at 119537664  (33,554,432)
// x2    bf16 [4][256][256][32]   at 153092096  (16,777,216)
// x3    f32  [4][256][256]       at 169869312  (1,048,576)
// wbf   bf16 packed fusion       at 170917888  (442,368)
// wb1   bf16 packed reg1         at 171360256  (110,592)
// wt2   f32  [kpos][32]          at 171470848  (3,456)

__global__ void omni_transpose_w(const float* __restrict__ src, float* __restrict__ dst,
                                 int cin, int cout, int n) {
    int i = blockIdx.x * 256 + threadIdx.x;
    if (i >= n) return;
    int co = i % cout;
    int t  = i / cout;
    int ci = t % cin;
    int kpos = t / cin;
    dst[i] = src[(co * cin + ci) * 27 + kpos];
}

// pack conv3d weights (OIDHW fp32) into MFMA B-fragment order, bf16.
// layout: [p = c*3+kd][f = tap*4+ks][wn][lane][8]
template<int CI, int CO>
__global__ void omni_pack_w(const float* __restrict__ w, ushort_t* __restrict__ dst) {
    constexpr int WN = CO / 32;
    const int n = (CI / 64) * 3 * 36 * WN * 512;
    int o = blockIdx.x * 256 + threadIdx.x;
    if (o >= n) return;
    const int j = o & 7;
    const int lane = (o >> 3) & 63;
    int r = o >> 9;
    const int wn = r % WN; r /= WN;
    const int f = r % 36;  const int p = r / 36;
    const int tap = f >> 2, ks = f & 3;
    const int c = p / 3, kd = p % 3;
    const int co = wn * 32 + (lane & 31);
    const int ci = c * 64 + ks * 16 + (lane >> 5) * 8 + j;
    const int ky = tap / 3, kx = tap % 3;
    dst[o] = f2bf(w[(((size_t)(co * CI + ci) * 3 + kd) * 3 + ky) * 3 + kx]);
}

// conv2d stride2 pad1 + relu; input NCHW [3,640,1280]; out bf16 channels-last [cam][320][640][32]
__global__ __launch_bounds__(256) void omni_feat_conv(
        const float* __restrict__ c0, const float* __restrict__ c1,
        const float* __restrict__ c2, const float* __restrict__ c3,
        const float* __restrict__ w, ushort_t* __restrict__ feat) {
    __shared__ float wl[864];
    int tid = threadIdx.x;
    for (int i = tid; i < 864; i += 256) wl[i] = w[i];
    __syncthreads();
    int gid = blockIdx.x * 256 + tid;               // 4*320*640
    int ox = gid % 640;
    int t = gid / 640;
    int oy = t % 320;
    int cam = t / 320;
    const float* src = (cam == 0) ? c0 : (cam == 1) ? c1 : (cam == 2) ? c2 : c3;
    float acc[32];
#pragma unroll
    for (int i = 0; i < 32; i++) acc[i] = 0.f;
    for (int ky = 0; ky < 3; ky++) {
        int iy = oy * 2 - 1 + ky;
        if (iy < 0 || iy >= 640) continue;
        for (int kx = 0; kx < 3; kx++) {
            int ix = ox * 2 - 1 + kx;
            if (ix < 0 || ix >= 1280) continue;
#pragma unroll
            for (int ci = 0; ci < 3; ci++) {
                float v = src[(ci * 640 + iy) * 1280 + ix];
#pragma unroll
                for (int co = 0; co < 32; co++)
                    acc[co] += v * wl[((co * 3 + ci) * 3 + ky) * 3 + kx];
            }
        }
    }
    uint4* d4 = (uint4*)(feat + (size_t)gid * 32);
#pragma unroll
    for (int q = 0; q < 4; q++) {
        uint4 v;
        v.x = pk2(fmaxf(acc[8*q+0],0.f), fmaxf(acc[8*q+1],0.f));
        v.y = pk2(fmaxf(acc[8*q+2],0.f), fmaxf(acc[8*q+3],0.f));
        v.z = pk2(fmaxf(acc[8*q+4],0.f), fmaxf(acc[8*q+5],0.f));
        v.w = pk2(fmaxf(acc[8*q+6],0.f), fmaxf(acc[8*q+7],0.f));
        d4[q] = v;
    }
}

// Tiled fused grid_sample + antialiased resize.
#define NXP 42
#define NYP 12
#define NPOS (NXP * NYP)   // 504
__global__ __launch_bounds__(256) void omni_warp_resize(
        const ushort_t* __restrict__ feat, const float* __restrict__ grids,
        ushort_t* __restrict__ costs) {
    __shared__ uint4 smp4[4 * NPOS];   // 32,256 B
    const int tid = threadIdx.x;
    const int bid = blockIdx.x;
    const int tx  = bid & 15;
    const int ty  = (bid >> 4) & 31;
    const int d   = (bid >> 9) & 3;
    const int cam = bid >> 11;
    const int x0 = tx * 16, y0 = ty * 8;
    const int jx_base = 40 * tx - 1;
    const int jy_base = 10 * ty - 1;
    const float* gbase = grids + ((size_t)(cam * 4 + d) * 320) * 640 * 2;
    const ushort_t* fbase = feat + (size_t)cam * 320 * 640 * 32;

    for (int i = tid; i < NPOS; i += 256) {
        const int jy = jy_base + i / NXP;
        const int jx = jx_base + i % NXP;
        float acc[32];
#pragma unroll
        for (int c = 0; c < 32; c++) acc[c] = 0.f;
        if ((unsigned)jy < 320u && (unsigned)jx < 640u) {
            const float gx = gbase[((size_t)jy * 640 + jx) * 2];
            const float gy = gbase[((size_t)jy * 640 + jx) * 2 + 1];
            const float fx = (gx + 1.f) * 320.f - 0.5f;
            const float fy = (gy + 1.f) * 160.f - 0.5f;
            const float x0f = floorf(fx), y0f = floorf(fy);
            const float ax = fx - x0f, ay = fy - y0f;
            const int sx0 = (int)x0f, sy0 = (int)y0f;
            const float tw[4] = {(1.f-ax)*(1.f-ay), ax*(1.f-ay), (1.f-ax)*ay, ax*ay};
            const int xs4[4] = {sx0, sx0+1, sx0, sx0+1};
            const int ys4[4] = {sy0, sy0, sy0+1, sy0+1};
#pragma unroll
            for (int tc = 0; tc < 4; tc++) {
                const int xi = xs4[tc], yi = ys4[tc];
                if (xi < 0 || xi >= 640 || yi < 0 || yi >= 320) continue;
                const float wt = tw[tc];
                const uint4* f4 = (const uint4*)(fbase + ((size_t)yi * 640 + xi) * 32);
#pragma unroll
                for (int q = 0; q < 4; q++) {
                    uint4 v = f4[q];
                    float2 p0 = bfp(v.x), p1 = bfp(v.y), p2 = bfp(v.z), p3 = bfp(v.w);
                    acc[8*q+0] += wt * p0.x; acc[8*q+1] += wt * p0.y;
                    acc[8*q+2] += wt * p1.x; acc[8*q+3] += wt * p1.y;
                    acc[8*q+4] += wt * p2.x; acc[8*q+5] += wt * p2.y;
                    acc[8*q+6] += wt * p3.x; acc[8*q+7] += wt * p3.y;
                }
            }
        }
#pragma unroll
        for (int q = 0; q < 4; q++) {
            uint4 v;
            v.x = pk2(acc[8*q+0], acc[8*q+1]);
            v.y = pk2(acc[8*q+2], acc[8*q+3]);
            v.z = pk2(acc[8*q+4], acc[8*q+5]);
            v.w = pk2(acc[8*q+6], acc[8*q+7]);
            smp4[q * NPOS + i] = v;
        }
    }
    __syncthreads();

    const int half = tid >> 7;
    const int p = tid & 127;
    const int x = x0 + (p & 15);
    const int y = y0 + (p >> 4);

    const float sy = 1.25f * y + 0.125f;
    const int jy0 = (int)ceilf(sy - 1.25f);
    float wy[3]; float sumy = 0.f;
#pragma unroll
    for (int t = 0; t < 3; t++) {
        int j = jy0 + t;
        float w = fmaxf(1.f - fabsf(sy - (float)j) * 0.8f, 0.f);
        if (j < 0 || j > 319) w = 0.f;
        wy[t] = w; sumy += w;
    }
    const float isy = 1.f / sumy;
    const float sx = 2.5f * x + 0.75f;
    const int jx0 = (int)ceilf(sx - 2.5f);
    float wx[5]; float sumx = 0.f;
#pragma unroll
    for (int t = 0; t < 5; t++) {
        int j = jx0 + t;
        float w = fmaxf(1.f - fabsf(sx - (float)j) * 0.4f, 0.f);
        if (j < 0 || j > 639) w = 0.f;
        wx[t] = w; sumx += w;
    }
    const float isx = 1.f / sumx;

    float acc[16];
#pragma unroll
    for (int c = 0; c < 16; c++) acc[c] = 0.f;
#pragma unroll
    for (int a = 0; a < 3; a++) {
        const float wya = wy[a] * isy;
        if (wya <= 0.f) continue;
        const int prow = (jy0 + a) - jy_base;
#pragma unroll
        for (int b = 0; b < 5; b++) {
            const float wr = wya * wx[b] * isx;
            if (wr <= 0.f) continue;
            const int pos = prow * NXP + (jx0 + b) - jx_base;
#pragma unroll
            for (int qq = 0; qq < 2; qq++) {
                uint4 v = smp4[(half * 2 + qq) * NPOS + pos];
                float2 p0 = bfp(v.x), p1 = bfp(v.y), p2 = bfp(v.z), p3 = bfp(v.w);
                acc[8*qq+0] += wr * p0.x; acc[8*qq+1] += wr * p0.y;
                acc[8*qq+2] += wr * p1.x; acc[8*qq+3] += wr * p1.y;
                acc[8*qq+4] += wr * p2.x; acc[8*qq+5] += wr * p2.y;
                acc[8*qq+6] += wr * p3.x; acc[8*qq+7] += wr * p3.y;
            }
        }
    }
    uint4* d4 = (uint4*)(costs + (((size_t)(d * 256 + y) * 256 + x) * 128) + cam * 32 + half * 16);
#pragma unroll
    for (int qq = 0; qq < 2; qq++) {
        uint4 v;
        v.x = pk2(acc[8*qq+0], acc[8*qq+1]);
        v.y = pk2(acc[8*qq+2], acc[8*qq+3]);
        v.z = pk2(acc[8*qq+4], acc[8*qq+5]);
        v.w = pk2(acc[8*qq+6], acc[8*qq+7]);
        d4[qq] = v;
    }
}

// MFMA implicit-GEMM conv3d (3x3x3, pad1) channels-last bf16, relu.
// XT=128 px, 4 waves each owning one 32-px m-tile and ALL couts (NR=CO/32
// accumulators): one A ds_read feeds NR MFMAs. B fragments are loaded
// per-tap from global (L2-resident) -> no 144-reg breg, occupancy up.
// A in LDS [ky][g][xl], xl padded to 133 === 5 (mod 8): conflict-free
// b128 reads (consecutive xl) and writes (g-cycling covers 32 banks).
template<int CI, int CO>
__global__ __launch_bounds__(256, 3) void omni_conv3d_mfma(
        const ushort_t* __restrict__ in,
        const ushort_t* __restrict__ wb,
        ushort_t* __restrict__ out) {
    constexpr int WN  = CO / 32;        // n-tiles per wave: 2 (fusion) / 1 (reg1)
    constexpr int XL  = 130;
    constexpr int XLP = 133;            // (133*4)%32 == 20 -> conflict-free
    constexpr int NIT = 3 * XL * 8;     // staging uint4 items
    __shared__ ushort_t lds[3 * 8 * XLP * 8];   // 51,072 B -> 3 blocks/CU
    const int tid = threadIdx.x;
    const int lane = tid & 63;
    const int wm = tid >> 6;
    const int x0 = blockIdx.x * 128;
    const int y  = blockIdx.y;
    const int d  = blockIdx.z;
    const int mrow = wm * 32 + (lane & 31);
    const int gc   = (lane >> 5);       // k half

    f32x16 acc[WN];
#pragma unroll
    for (int nr = 0; nr < WN; ++nr)
#pragma unroll
        for (int r = 0; r < 16; ++r) acc[nr][r] = 0.f;

    for (int c = 0; c < CI / 64; ++c) {
        for (int kd = 0; kd < 3; ++kd) {
            const int dd = d + kd - 1;
            if (dd < 0 || dd > 3) continue;            // block-uniform
            __syncthreads();
            for (int i = tid; i < NIT; i += 256) {
                const int g  = i & 7;
                const int xl = (i >> 3) % XL;
                const int yy = (i >> 3) / XL;
                const int gy = y - 1 + yy;
                const int gx = x0 - 1 + xl;
                uint4 v = make_uint4(0u, 0u, 0u, 0u);
                if ((unsigned)gy < 256u && (unsigned)gx < 256u)
                    v = *(const uint4*)(in + (((size_t)dd * 256 + gy) * 256 + gx) * CI + c * 64 + g * 8);
                *(uint4*)&lds[((yy * 8 + g) * XLP + xl) * 8] = v;
            }
            __syncthreads();
            const int p = c * 3 + kd;
            const ushort_t* wbp = wb + (size_t)p * 36 * WN * 512 + lane * 8;
#pragma unroll
            for (int ky = 0; ky < 3; ++ky) {
                const int gyy = y - 1 + ky;
                if ((unsigned)gyy >= 256u) continue;   // block-uniform
#pragma unroll
                for (int kx = 0; kx < 3; ++kx) {
                    const int xl = mrow + kx;
                    const int f0 = (ky * 3 + kx) * 4;
#pragma unroll
                    for (int ks = 0; ks < 4; ++ks) {
                        const int g = ks * 2 + gc;
                        const bfrag a = *(const bfrag*)&lds[((ky * 8 + g) * XLP + xl) * 8];
#pragma unroll
                        for (int nr = 0; nr < WN; ++nr) {
                            const bfrag b = *(const bfrag*)(wbp + (size_t)((f0 + ks) * WN + nr) * 512);
                            acc[nr] = __builtin_amdgcn_mfma_f32_32x32x16_bf16(a, b, acc[nr], 0, 0, 0);
                        }
                    }
                }
            }
        }
    }
    // epilogue: relu + bf16 store. C/D: col=lane&31, row=(r&3)+8*(r>>2)+4*(lane>>5)
#pragma unroll
    for (int nr = 0; nr < WN; ++nr) {
#pragma unroll
        for (int r = 0; r < 16; ++r) {
            const int row = (r & 3) + 8 * (r >> 2) + 4 * gc;
            const int px  = x0 + wm * 32 + row;
            const int co  = nr * 32 + (lane & 31);
            out[((size_t)(d * 256 + y) * 256 + px) * CO + co] = f2bf(fmaxf(acc[nr][r], 0.f));
        }
    }
}

// conv3d 32->1, bf16 in, wt2 fp32 [kpos][ci]
__global__ __launch_bounds__(256) void omni_reg2(
        const ushort_t* __restrict__ in, const float* __restrict__ wt2,
        float* __restrict__ out) {
    __shared__ float wl[27 * 32];
    int tid = threadIdx.x;
    for (int i = tid; i < 864; i += 256) wl[i] = wt2[i];
    __syncthreads();
    int gid = blockIdx.x * 256 + tid;               // 4*256*256
    int x = gid & 255;
    int y = (gid >> 8) & 255;
    int d = gid >> 16;
    float acc = 0.f;
    for (int kd = 0; kd < 3; kd++) {
        int dd = d + kd - 1; if (dd < 0 || dd > 3) continue;
        for (int ky = 0; ky < 3; ky++) {
            int yy = y + ky - 1; if (yy < 0 || yy > 255) continue;
            for (int kx = 0; kx < 3; kx++) {
                int xx = x + kx - 1; if (xx < 0 || xx > 255) continue;
                const uint4* f4 = (const uint4*)(in + (((size_t)dd * 256 + yy) * 256 + xx) * 32);
                const float* wp = &wl[((kd * 3 + ky) * 3 + kx) * 32];
#pragma unroll
                for (int q = 0; q < 4; q++) {
                    uint4 v = f4[q];
                    float2 p0 = bfp(v.x), p1 = bfp(v.y), p2 = bfp(v.z), p3 = bfp(v.w);
                    acc += p0.x * wp[8*q+0] + p0.y * wp[8*q+1]
                         + p1.x * wp[8*q+2] + p1.y * wp[8*q+3]
                         + p2.x * wp[8*q+4] + p2.y * wp[8*q+5]
                         + p3.x * wp[8*q+6] + p3.y * wp[8*q+7];
                }
            }
        }
    }
    out[gid] = acc;
}

// depth resize 4->8 + softmax + expectation
__global__ __launch_bounds__(256) void omni_disp(
        const float* __restrict__ x3, float* __restrict__ out) {
    int gid = blockIdx.x * 256 + threadIdx.x;       // 65536
    float v0 = x3[gid];
    float v1 = x3[65536 + gid];
    float v2 = x3[2 * 65536 + gid];
    float v3 = x3[3 * 65536 + gid];
    float l[8];
    l[0] = v0;
    l[1] = 0.75f * v0 + 0.25f * v1;
    l[2] = 0.25f * v0 + 0.75f * v1;
    l[3] = 0.75f * v1 + 0.25f * v2;
    l[4] = 0.25f * v1 + 0.75f * v2;
    l[5] = 0.75f * v2 + 0.25f * v3;
    l[6] = 0.25f * v2 + 0.75f * v3;
    l[7] = v3;
    float m = l[0];
#pragma unroll
    for (int i = 1; i < 8; i++) m = fmaxf(m, l[i]);
    float s = 0.f, e = 0.f;
#pragma unroll
    for (int i = 0; i < 8; i++) {
        float p = expf(l[i] - m);
        s += p; e += p * (float)i;
    }
    out[gid] = e / s;
}

extern "C" void kernel_launch(void* const* d_in, const int* in_sizes, int n_in,
                              void* d_out, int out_size, void* d_ws, size_t ws_size,
                              hipStream_t stream) {
    const float* cam0 = (const float*)d_in[0];
    const float* cam1 = (const float*)d_in[1];
    const float* cam2 = (const float*)d_in[2];
    const float* cam3 = (const float*)d_in[3];
    const float* grids = (const float*)d_in[4];
    const float* w_feat = (const float*)d_in[5];
    const float* w_fusion = (const float*)d_in[6];
    const float* w_reg1 = (const float*)d_in[7];
    const float* w_reg2 = (const float*)d_in[8];

    char* base = (char*)d_ws;
    ushort_t* feat  = (ushort_t*)(base);
    ushort_t* costs = (ushort_t*)(base + 52428800);
    ushort_t* x1    = (ushort_t*)(base + 119537664);
    ushort_t* x2    = (ushort_t*)(base + 153092096);
    float*    x3    = (float*)   (base + 169869312);
    ushort_t* wbf   = (ushort_t*)(base + 170917888);
    ushort_t* wb1   = (ushort_t*)(base + 171360256);
    float*    wt2   = (float*)   (base + 171470848);

    omni_pack_w<128, 64><<<864, 256, 0, stream>>>(w_fusion, wbf);
    omni_pack_w<64, 32><<<216, 256, 0, stream>>>(w_reg1, wb1);
    omni_transpose_w<<<4, 256, 0, stream>>>(w_reg2, wt2, 32, 1, 864);

    omni_feat_conv<<<3200, 256, 0, stream>>>(cam0, cam1, cam2, cam3, w_feat, feat);
    omni_warp_resize<<<8192, 256, 0, stream>>>(feat, grids, costs);
    omni_conv3d_mfma<128, 64><<<dim3(2, 256, 4), 256, 0, stream>>>(costs, wbf, x1);
    omni_conv3d_mfma<64, 32><<<dim3(2, 256, 4), 256, 0, stream>>>(x1, wb1, x2);
    omni_reg2<<<1024, 256, 0, stream>>>(x2, wt2, x3);
    omni_disp<<<256, 256, 0, stream>>>(x3, (float*)d_out);
}

// Round 7
// 541.340 us; speedup vs baseline: 1.1442x; 1.0842x over previous
//
#include <hip/hip_runtime.h>

typedef __attribute__((ext_vector_type(8))) __bf16 bfrag;
typedef __attribute__((ext_vector_type(16))) float f32x16;
typedef unsigned short ushort_t;

__device__ __forceinline__ unsigned short f2bf(float f) {
    union { unsigned int u; float f; } c; c.f = f;
    unsigned int u = c.u;
    return (unsigned short)((u + 0x7FFFu + ((u >> 16) & 1u)) >> 16);
}
__device__ __forceinline__ float2 bfp(unsigned int u) {
    union { unsigned int u; float f; } lo, hi;
    lo.u = u << 16; hi.u = u & 0xFFFF0000u;
    return make_float2(lo.f, hi.f);
}
__device__ __forceinline__ unsigned int pk2(float a, float b) {
    return ((unsigned)f2bf(b) << 16) | f2bf(a);
}

// ---------------- workspace layout (bytes) ----------------
// feat  bf16 [4][320][640][32]   at 0          (52,428,800)
// costs bf16 [4][256][256][128]  at 52428800   (67,108,864)
// x1    bf16 [4][256][256][64]   at 119537664  (33,554,432)
// x2    bf16 [4][256][256][32]   at 153092096  (16,777,216)
// x3    f32  [4][256][256]       at 169869312  (1,048,576)
// wbf   bf16 packed fusion       at 170917888  (442,368)
// wb1   bf16 packed reg1         at 171360256  (110,592)
// wt2   f32  [kpos][32]          at 171470848  (3,456)

__global__ void omni_transpose_w(const float* __restrict__ src, float* __restrict__ dst,
                                 int cin, int cout, int n) {
    int i = blockIdx.x * 256 + threadIdx.x;
    if (i >= n) return;
    int co = i % cout;
    int t  = i / cout;
    int ci = t % cin;
    int kpos = t / cin;
    dst[i] = src[(co * cin + ci) * 27 + kpos];
}

// pack conv3d weights (OIDHW fp32) into MFMA B-fragment order, bf16.
// layout: [p = c*3+kd][f = tap*4+ks][wn][lane][8]
template<int CI, int CO>
__global__ void omni_pack_w(const float* __restrict__ w, ushort_t* __restrict__ dst) {
    constexpr int WN = CO / 32;
    const int n = (CI / 64) * 3 * 36 * WN * 512;
    int o = blockIdx.x * 256 + threadIdx.x;
    if (o >= n) return;
    const int j = o & 7;
    const int lane = (o >> 3) & 63;
    int r = o >> 9;
    const int wn = r % WN; r /= WN;
    const int f = r % 36;  const int p = r / 36;
    const int tap = f >> 2, ks = f & 3;
    const int c = p / 3, kd = p % 3;
    const int co = wn * 32 + (lane & 31);
    const int ci = c * 64 + ks * 16 + (lane >> 5) * 8 + j;
    const int ky = tap / 3, kx = tap % 3;
    dst[o] = f2bf(w[(((size_t)(co * CI + ci) * 3 + kd) * 3 + ky) * 3 + kx]);
}

// conv2d stride2 pad1 + relu; input NCHW [3,640,1280]; out bf16 channels-last [cam][320][640][32]
__global__ __launch_bounds__(256) void omni_feat_conv(
        const float* __restrict__ c0, const float* __restrict__ c1,
        const float* __restrict__ c2, const float* __restrict__ c3,
        const float* __restrict__ w, ushort_t* __restrict__ feat) {
    __shared__ float wl[864];
    int tid = threadIdx.x;
    for (int i = tid; i < 864; i += 256) wl[i] = w[i];
    __syncthreads();
    int gid = blockIdx.x * 256 + tid;               // 4*320*640
    int ox = gid % 640;
    int t = gid / 640;
    int oy = t % 320;
    int cam = t / 320;
    const float* src = (cam == 0) ? c0 : (cam == 1) ? c1 : (cam == 2) ? c2 : c3;
    float acc[32];
#pragma unroll
    for (int i = 0; i < 32; i++) acc[i] = 0.f;
    for (int ky = 0; ky < 3; ky++) {
        int iy = oy * 2 - 1 + ky;
        if (iy < 0 || iy >= 640) continue;
        for (int kx = 0; kx < 3; kx++) {
            int ix = ox * 2 - 1 + kx;
            if (ix < 0 || ix >= 1280) continue;
#pragma unroll
            for (int ci = 0; ci < 3; ci++) {
                float v = src[(ci * 640 + iy) * 1280 + ix];
#pragma unroll
                for (int co = 0; co < 32; co++)
                    acc[co] += v * wl[((co * 3 + ci) * 3 + ky) * 3 + kx];
            }
        }
    }
    uint4* d4 = (uint4*)(feat + (size_t)gid * 32);
#pragma unroll
    for (int q = 0; q < 4; q++) {
        uint4 v;
        v.x = pk2(fmaxf(acc[8*q+0],0.f), fmaxf(acc[8*q+1],0.f));
        v.y = pk2(fmaxf(acc[8*q+2],0.f), fmaxf(acc[8*q+3],0.f));
        v.z = pk2(fmaxf(acc[8*q+4],0.f), fmaxf(acc[8*q+5],0.f));
        v.w = pk2(fmaxf(acc[8*q+6],0.f), fmaxf(acc[8*q+7],0.f));
        d4[q] = v;
    }
}

// Tiled fused grid_sample + antialiased resize.
#define NXP 42
#define NYP 12
#define NPOS (NXP * NYP)   // 504
__global__ __launch_bounds__(256, 5) void omni_warp_resize(
        const ushort_t* __restrict__ feat, const float* __restrict__ grids,
        ushort_t* __restrict__ costs) {
    __shared__ uint4 smp4[4 * NPOS];   // 32,256 B -> 5 blocks/CU
    const int tid = threadIdx.x;
    const int bid = blockIdx.x;
    const int tx  = bid & 15;
    const int ty  = (bid >> 4) & 31;
    const int d   = (bid >> 9) & 3;
    const int cam = bid >> 11;
    const int x0 = tx * 16, y0 = ty * 8;
    const int jx_base = 40 * tx - 1;
    const int jy_base = 10 * ty - 1;
    const float* gbase = grids + ((size_t)(cam * 4 + d) * 320) * 640 * 2;
    const ushort_t* fbase = feat + (size_t)cam * 320 * 640 * 32;

    for (int i = tid; i < NPOS; i += 256) {
        const int jy = jy_base + i / NXP;
        const int jx = jx_base + i % NXP;
        float acc[32];
#pragma unroll
        for (int c = 0; c < 32; c++) acc[c] = 0.f;
        if ((unsigned)jy < 320u && (unsigned)jx < 640u) {
            const float gx = gbase[((size_t)jy * 640 + jx) * 2];
            const float gy = gbase[((size_t)jy * 640 + jx) * 2 + 1];
            const float fx = (gx + 1.f) * 320.f - 0.5f;
            const float fy = (gy + 1.f) * 160.f - 0.5f;
            const float x0f = floorf(fx), y0f = floorf(fy);
            const float ax = fx - x0f, ay = fy - y0f;
            const int sx0 = (int)x0f, sy0 = (int)y0f;
            const float tw[4] = {(1.f-ax)*(1.f-ay), ax*(1.f-ay), (1.f-ax)*ay, ax*ay};
            const int xs4[4] = {sx0, sx0+1, sx0, sx0+1};
            const int ys4[4] = {sy0, sy0, sy0+1, sy0+1};
#pragma unroll
            for (int tc = 0; tc < 4; tc++) {
                const int xi = xs4[tc], yi = ys4[tc];
                if (xi < 0 || xi >= 640 || yi < 0 || yi >= 320) continue;
                const float wt = tw[tc];
                const uint4* f4 = (const uint4*)(fbase + ((size_t)yi * 640 + xi) * 32);
#pragma unroll
                for (int q = 0; q < 4; q++) {
                    uint4 v = f4[q];
                    float2 p0 = bfp(v.x), p1 = bfp(v.y), p2 = bfp(v.z), p3 = bfp(v.w);
                    acc[8*q+0] += wt * p0.x; acc[8*q+1] += wt * p0.y;
                    acc[8*q+2] += wt * p1.x; acc[8*q+3] += wt * p1.y;
                    acc[8*q+4] += wt * p2.x; acc[8*q+5] += wt * p2.y;
                    acc[8*q+6] += wt * p3.x; acc[8*q+7] += wt * p3.y;
                }
            }
        }
#pragma unroll
        for (int q = 0; q < 4; q++) {
            uint4 v;
            v.x = pk2(acc[8*q+0], acc[8*q+1]);
            v.y = pk2(acc[8*q+2], acc[8*q+3]);
            v.z = pk2(acc[8*q+4], acc[8*q+5]);
            v.w = pk2(acc[8*q+6], acc[8*q+7]);
            smp4[q * NPOS + i] = v;
        }
    }
    __syncthreads();

    const int half = tid >> 7;
    const int p = tid & 127;
    const int x = x0 + (p & 15);
    const int y = y0 + (p >> 4);

    const float sy = 1.25f * y + 0.125f;
    const int jy0 = (int)ceilf(sy - 1.25f);
    float wy[3]; float sumy = 0.f;
#pragma unroll
    for (int t = 0; t < 3; t++) {
        int j = jy0 + t;
        float w = fmaxf(1.f - fabsf(sy - (float)j) * 0.8f, 0.f);
        if (j < 0 || j > 319) w = 0.f;
        wy[t] = w; sumy += w;
    }
    const float isy = 1.f / sumy;
    const float sx = 2.5f * x + 0.75f;
    const int jx0 = (int)ceilf(sx - 2.5f);
    float wx[5]; float sumx = 0.f;
#pragma unroll
    for (int t = 0; t < 5; t++) {
        int j = jx0 + t;
        float w = fmaxf(1.f - fabsf(sx - (float)j) * 0.4f, 0.f);
        if (j < 0 || j > 639) w = 0.f;
        wx[t] = w; sumx += w;
    }
    const float isx = 1.f / sumx;

    float acc[16];
#pragma unroll
    for (int c = 0; c < 16; c++) acc[c] = 0.f;
#pragma unroll
    for (int a = 0; a < 3; a++) {
        const float wya = wy[a] * isy;
        if (wya <= 0.f) continue;
        const int prow = (jy0 + a) - jy_base;
#pragma unroll
        for (int b = 0; b < 5; b++) {
            const float wr = wya * wx[b] * isx;
            if (wr <= 0.f) continue;
            const int pos = prow * NXP + (jx0 + b) - jx_base;
#pragma unroll
            for (int qq = 0; qq < 2; qq++) {
                uint4 v = smp4[(half * 2 + qq) * NPOS + pos];
                float2 p0 = bfp(v.x), p1 = bfp(v.y), p2 = bfp(v.z), p3 = bfp(v.w);
                acc[8*qq+0] += wr * p0.x; acc[8*qq+1] += wr * p0.y;
                acc[8*qq+2] += wr * p1.x; acc[8*qq+3] += wr * p1.y;
                acc[8*qq+4] += wr * p2.x; acc[8*qq+5] += wr * p2.y;
                acc[8*qq+6] += wr * p3.x; acc[8*qq+7] += wr * p3.y;
            }
        }
    }
    uint4* d4 = (uint4*)(costs + (((size_t)(d * 256 + y) * 256 + x) * 128) + cam * 32 + half * 16);
#pragma unroll
    for (int qq = 0; qq < 2; qq++) {
        uint4 v;
        v.x = pk2(acc[8*qq+0], acc[8*qq+1]);
        v.y = pk2(acc[8*qq+2], acc[8*qq+3]);
        v.z = pk2(acc[8*qq+4], acc[8*qq+5]);
        v.w = pk2(acc[8*qq+6], acc[8*qq+7]);
        d4[qq] = v;
    }
}

// MFMA implicit-GEMM conv3d (3x3x3, pad1) channels-last bf16, relu.
// Tile: XT=64 px x YB=2 output rows. 4 waves = 2 x-halves x 2 y-rows; each
// wave 32 px x CO couts (NR=WN accumulators; one A ds_read feeds WN MFMAs).
// A window (4 rows x 66 px x 64ci) in LDS [row][g][xl], xl padded to 69
// (=5 mod 8): conflict-free b128 read/write. OOB y rows are zero-staged
// (pad-0 conv), so no ky skip. B loaded per-tap from global (L1/L2-hot).
template<int CI, int CO>
__global__ __launch_bounds__(256, 4) void omni_conv3d_mfma(
        const ushort_t* __restrict__ in,
        const ushort_t* __restrict__ wb,
        ushort_t* __restrict__ out) {
    constexpr int WN  = CO / 32;        // 2 (fusion) / 1 (reg1)
    constexpr int XL  = 66;
    constexpr int XLP = 69;             // (69*4)%32 == 20 -> conflict-free
    constexpr int NIT = 4 * XL * 8;     // 2112 staging uint4 items
    __shared__ ushort_t lds[4 * 8 * XLP * 8];   // 35,328 B -> 4 blocks/CU
    const int tid = threadIdx.x;
    const int lane = tid & 63;
    const int wid = tid >> 6;
    const int wx = wid & 1;             // x-half
    const int wy = wid >> 1;            // y-row
    const int x0 = blockIdx.x * 64;
    const int y0 = blockIdx.y * 2;
    const int d  = blockIdx.z;
    const int col = wx * 32 + (lane & 31);
    const int gc  = lane >> 5;          // k half

    f32x16 acc[WN];
#pragma unroll
    for (int nr = 0; nr < WN; ++nr)
#pragma unroll
        for (int r = 0; r < 16; ++r) acc[nr][r] = 0.f;

    for (int c = 0; c < CI / 64; ++c) {
        for (int kd = 0; kd < 3; ++kd) {
            const int dd = d + kd - 1;
            if (dd < 0 || dd > 3) continue;            // block-uniform
            __syncthreads();
            for (int i = tid; i < NIT; i += 256) {
                const int g  = i & 7;
                const int xl = (i >> 3) % XL;
                const int yy = (i >> 3) / XL;
                const int gy = y0 - 1 + yy;
                const int gx = x0 - 1 + xl;
                uint4 v = make_uint4(0u, 0u, 0u, 0u);
                if ((unsigned)gy < 256u && (unsigned)gx < 256u)
                    v = *(const uint4*)(in + (((size_t)dd * 256 + gy) * 256 + gx) * CI + c * 64 + g * 8);
                *(uint4*)&lds[((yy * 8 + g) * XLP + xl) * 8] = v;
            }
            __syncthreads();
            const int p = c * 3 + kd;
            const ushort_t* wbp = wb + (size_t)p * 36 * WN * 512 + lane * 8;
#pragma unroll
            for (int ky = 0; ky < 3; ++ky) {
                const int arow = ky + wy;              // staged row 0..3
#pragma unroll
                for (int kx = 0; kx < 3; ++kx) {
                    const int xl = col + kx;
                    const int f0 = (ky * 3 + kx) * 4;
#pragma unroll
                    for (int ks = 0; ks < 4; ++ks) {
                        const int g = ks * 2 + gc;
                        const bfrag a = *(const bfrag*)&lds[((arow * 8 + g) * XLP + xl) * 8];
#pragma unroll
                        for (int nr = 0; nr < WN; ++nr) {
                            const bfrag b = *(const bfrag*)(wbp + (size_t)((f0 + ks) * WN + nr) * 512);
                            acc[nr] = __builtin_amdgcn_mfma_f32_32x32x16_bf16(a, b, acc[nr], 0, 0, 0);
                        }
                    }
                }
            }
        }
    }
    // epilogue: relu + bf16 store. C/D: col=lane&31, row=(r&3)+8*(r>>2)+4*(lane>>5)
    const int yo = y0 + wy;
#pragma unroll
    for (int nr = 0; nr < WN; ++nr) {
#pragma unroll
        for (int r = 0; r < 16; ++r) {
            const int row = (r & 3) + 8 * (r >> 2) + 4 * gc;
            const int px  = x0 + wx * 32 + row;
            const int co  = nr * 32 + (lane & 31);
            out[((size_t)(d * 256 + yo) * 256 + px) * CO + co] = f2bf(fmaxf(acc[nr][r], 0.f));
        }
    }
}

// conv3d 32->1, bf16 in, wt2 fp32 [kpos][ci]
__global__ __launch_bounds__(256) void omni_reg2(
        const ushort_t* __restrict__ in, const float* __restrict__ wt2,
        float* __restrict__ out) {
    __shared__ float wl[27 * 32];
    int tid = threadIdx.x;
    for (int i = tid; i < 864; i += 256) wl[i] = wt2[i];
    __syncthreads();
    int gid = blockIdx.x * 256 + tid;               // 4*256*256
    int x = gid & 255;
    int y = (gid >> 8) & 255;
    int d = gid >> 16;
    float acc = 0.f;
    for (int kd = 0; kd < 3; kd++) {
        int dd = d + kd - 1; if (dd < 0 || dd > 3) continue;
        for (int ky = 0; ky < 3; ky++) {
            int yy = y + ky - 1; if (yy < 0 || yy > 255) continue;
            for (int kx = 0; kx < 3; kx++) {
                int xx = x + kx - 1; if (xx < 0 || xx > 255) continue;
                const uint4* f4 = (const uint4*)(in + (((size_t)dd * 256 + yy) * 256 + xx) * 32);
                const float* wp = &wl[((kd * 3 + ky) * 3 + kx) * 32];
#pragma unroll
                for (int q = 0; q < 4; q++) {
                    uint4 v = f4[q];
                    float2 p0 = bfp(v.x), p1 = bfp(v.y), p2 = bfp(v.z), p3 = bfp(v.w);
                    acc += p0.x * wp[8*q+0] + p0.y * wp[8*q+1]
                         + p1.x * wp[8*q+2] + p1.y * wp[8*q+3]
                         + p2.x * wp[8*q+4] + p2.y * wp[8*q+5]
                         + p3.x * wp[8*q+6] + p3.y * wp[8*q+7];
                }
            }
        }
    }
    out[gid] = acc;
}

// depth resize 4->8 + softmax + expectation
__global__ __launch_bounds__(256) void omni_disp(
        const float* __restrict__ x3, float* __restrict__ out) {
    int gid = blockIdx.x * 256 + threadIdx.x;       // 65536
    float v0 = x3[gid];
    float v1 = x3[65536 + gid];
    float v2 = x3[2 * 65536 + gid];
    float v3 = x3[3 * 65536 + gid];
    float l[8];
    l[0] = v0;
    l[1] = 0.75f * v0 + 0.25f * v1;
    l[2] = 0.25f * v0 + 0.75f * v1;
    l[3] = 0.75f * v1 + 0.25f * v2;
    l[4] = 0.25f * v1 + 0.75f * v2;
    l[5] = 0.75f * v2 + 0.25f * v3;
    l[6] = 0.25f * v2 + 0.75f * v3;
    l[7] = v3;
    float m = l[0];
#pragma unroll
    for (int i = 1; i < 8; i++) m = fmaxf(m, l[i]);
    float s = 0.f, e = 0.f;
#pragma unroll
    for (int i = 0; i < 8; i++) {
        float p = expf(l[i] - m);
        s += p; e += p * (float)i;
    }
    out[gid] = e / s;
}

extern "C" void kernel_launch(void* const* d_in, const int* in_sizes, int n_in,
                              void* d_out, int out_size, void* d_ws, size_t ws_size,
                              hipStream_t stream) {
    const float* cam0 = (const float*)d_in[0];
    const float* cam1 = (const float*)d_in[1];
    const float* cam2 = (const float*)d_in[2];
    const float* cam3 = (const float*)d_in[3];
    const float* grids = (const float*)d_in[4];
    const float* w_feat = (const float*)d_in[5];
    const float* w_fusion = (const float*)d_in[6];
    const float* w_reg1 = (const float*)d_in[7];
    const float* w_reg2 = (const float*)d_in[8];

    char* base = (char*)d_ws;
    ushort_t* feat  = (ushort_t*)(base);
    ushort_t* costs = (ushort_t*)(base + 52428800);
    ushort_t* x1    = (ushort_t*)(base + 119537664);
    ushort_t* x2    = (ushort_t*)(base + 153092096);
    float*    x3    = (float*)   (base + 169869312);
    ushort_t* wbf   = (ushort_t*)(base + 170917888);
    ushort_t* wb1   = (ushort_t*)(base + 171360256);
    float*    wt2   = (float*)   (base + 171470848);

    omni_pack_w<128, 64><<<864, 256, 0, stream>>>(w_fusion, wbf);
    omni_pack_w<64, 32><<<216, 256, 0, stream>>>(w_reg1, wb1);
    omni_transpose_w<<<4, 256, 0, stream>>>(w_reg2, wt2, 32, 1, 864);

    omni_feat_conv<<<3200, 256, 0, stream>>>(cam0, cam1, cam2, cam3, w_feat, feat);
    omni_warp_resize<<<8192, 256, 0, stream>>>(feat, grids, costs);
    omni_conv3d_mfma<128, 64><<<dim3(4, 128, 4), 256, 0, stream>>>(costs, wbf, x1);
    omni_conv3d_mfma<64, 32><<<dim3(4, 128, 4), 256, 0, stream>>>(x1, wb1, x2);
    omni_reg2<<<1024, 256, 0, stream>>>(x2, wt2, x3);
    omni_disp<<<256, 256, 0, stream>>>(x3, (float*)d_out);
}